// Round 7
// baseline (550.398 us; speedup 1.0000x reference)
//
#include <hip/hip_runtime.h>
#include <math.h>

// Problem constants (match reference)
constexpr int EN = 200000;   // edges == nodes
constexpr int D  = 128;      // embedding dim
constexpr int R  = 4;        // relation types
constexpr float NEG = 0.01f;
constexpr int CPB = 32;      // columns per phaseB block

static inline int ceil_div(int a, int b) { return (a + b - 1) / b; }

typedef __attribute__((ext_vector_type(8))) __bf16 bf16x8;
typedef __attribute__((ext_vector_type(4))) float f32x4;

// ---------- bf16 helpers (RNE) ----------
__device__ __forceinline__ unsigned short f2bf(float f) {
    union { float f; unsigned u; } v; v.f = f;
    unsigned u = v.u + 0x7fffu + ((v.u >> 16) & 1u);
    return (unsigned short)(u >> 16);
}
__device__ __forceinline__ unsigned pack2bf(float a, float b) {
    return (unsigned)f2bf(a) | ((unsigned)f2bf(b) << 16);
}
__device__ __forceinline__ float bflo(unsigned m) { return __uint_as_float(m << 16); }
__device__ __forceinline__ float bfhi(unsigned m) { return __uint_as_float(m & 0xffff0000u); }

// ---------- histogram: col degree (int) + relation counts ----------
__global__ void k_cnt(const int* __restrict__ col, const int* __restrict__ etype,
                      int* __restrict__ cnt, int* __restrict__ rcnt, int n) {
    __shared__ int lr[R];
    int t = threadIdx.x;
    if (t < R) lr[t] = 0;
    __syncthreads();
    int e = blockIdx.x * 256 + t;
    if (e < n) {
        atomicAdd(&cnt[col[e]], 1);
        atomicAdd(&lr[etype[e]], 1);
    }
    __syncthreads();
    if (t < R) atomicAdd(&rcnt[t], lr[t]);
}

// ---------- W pre-swizzle to 16x16x32 MFMA A-frag bf16 (R5 layout) ----------
__device__ __forceinline__ void wswz_one(const float* __restrict__ w,
                                         unsigned short* __restrict__ wsw, int t) {
    int lane = t & 63, mt = (t >> 6) & 7, s = (t >> 9) & 3, r = t >> 11;
    int q = lane >> 4, n = mt * 16 + (lane & 15);
    union { unsigned short us[8]; uint4 u4; } o;
    #pragma unroll
    for (int j = 0; j < 8; ++j) {
        int k = s * 32 + q * 8 + j;
        o.us[j] = f2bf(w[((size_t)r * D + k) * D + n]);
    }
    *(uint4*)(wsw + (size_t)t * 8) = o.u4;
}

// ---------- scan stage 1 (+ fused weight prep in extra blocks) ----------
__global__ void k_scan1(const int* __restrict__ cnt, int* __restrict__ part, int n, int nScan,
                        const float* __restrict__ w1, const float* __restrict__ w2,
                        const float* __restrict__ w3,
                        unsigned short* __restrict__ w2b, unsigned short* __restrict__ w3b,
                        float* __restrict__ s1) {
    if (blockIdx.x >= nScan) {
        int t = (blockIdx.x - nScan) * 256 + threadIdx.x;
        if (t < 8192) {
            wswz_one(w2, w2b, t);
        } else if (t < 16384) {
            wswz_one(w3, w3b, t - 8192);
        } else if (t < 16896) {
            int t2 = t - 16384;           // 0..511: colsum(W1)
            int r = t2 >> 7, j = t2 & (D - 1);
            float s = 0.f;
            for (int k = 0; k < D; ++k) s += w1[((r << 7) + k) * D + j];
            s1[t2] = s;
        }
        return;
    }
    __shared__ int sm[256];
    int t = threadIdx.x;
    int base = blockIdx.x * 1024 + t * 4;
    int s = 0;
    #pragma unroll
    for (int i = 0; i < 4; ++i) { int idx = base + i; if (idx < n) s += cnt[idx]; }
    sm[t] = s; __syncthreads();
    for (int off = 128; off > 0; off >>= 1) {
        if (t < off) sm[t] += sm[t + off];
        __syncthreads();
    }
    if (t == 0) part[blockIdx.x] = sm[0];
}

// ---------- scan stage 2 (+ relation bases + bk_row pad zero) ----------
__global__ void k_scan2(int* __restrict__ part, int nb,
                        const int* __restrict__ rcnt, int* __restrict__ rbase,
                        int* __restrict__ cursor, int* __restrict__ col_start,
                        int* __restrict__ bk_row) {
    __shared__ int sm[256];
    int t = threadIdx.x;
    sm[t] = (t < nb) ? part[t] : 0;
    __syncthreads();
    for (int off = 1; off < 256; off <<= 1) {
        int u = 0;
        if (t >= off) u = sm[t - off];
        __syncthreads();
        sm[t] += u;
        __syncthreads();
    }
    int ex = (t > 0) ? sm[t - 1] : 0;
    if (t < nb) part[t] = ex;
    if (t == 0) {
        int s = 0;
        for (int r = 0; r < R; ++r) { rbase[r] = s; cursor[r] = s; s += rcnt[r]; }
        rbase[R] = s;
        col_start[EN] = EN;
    }
    if (t >= 64 && t < 128) bk_row[EN + t - 64] = 0;   // pad: safe gather rows
}

// ---------- scan stage 3: col_start (+ ccur zeroing) ----------
__global__ void k_scan3(const int* __restrict__ cnt, const int* __restrict__ part,
                        int* __restrict__ col_start, int* __restrict__ ccur, int n) {
    __shared__ int sm[256];
    int t = threadIdx.x;
    int base = blockIdx.x * 1024 + t * 4;
    int v[4]; int s = 0;
    #pragma unroll
    for (int i = 0; i < 4; ++i) { int idx = base + i; v[i] = (idx < n) ? cnt[idx] : 0; s += v[i]; }
    sm[t] = s; __syncthreads();
    for (int off = 1; off < 256; off <<= 1) {
        int u = 0;
        if (t >= off) u = sm[t - off];
        __syncthreads();
        sm[t] += u;
        __syncthreads();
    }
    int ex = ((t > 0) ? sm[t - 1] : 0) + part[blockIdx.x];
    #pragma unroll
    for (int i = 0; i < 4; ++i) {
        int idx = base + i;
        if (idx < n) { col_start[idx] = ex; ex += v[i]; ccur[idx] = 0; }
    }
}

// ---------- bucket by relation + col-sorted placement + coef ----------
__global__ void k_bucket(const int* __restrict__ row, const int* __restrict__ col,
                         const int* __restrict__ etype, const float* __restrict__ attr,
                         const int* __restrict__ cnt, const int* __restrict__ col_start,
                         int* __restrict__ cursor, int* __restrict__ ccur,
                         int* __restrict__ bk_row, int* __restrict__ bk_dst,
                         float* __restrict__ bk_coef,
                         float* __restrict__ scoef, unsigned char* __restrict__ styp,
                         int n) {
    __shared__ int lcnt[R];
    __shared__ int lbase[R];
    int t = threadIdx.x;
    if (t < R) lcnt[t] = 0;
    __syncthreads();
    int e = blockIdx.x * 256 + t;
    int r = 0, rank = 0, c = 0, rw = 0;
    float cf = 0.f;
    if (e < n) {
        r = etype[e];
        rank = atomicAdd(&lcnt[r], 1);
        c = col[e]; rw = row[e];
        int dr = cnt[rw], dc = cnt[c];
        float a = (dr > 0) ? rsqrtf((float)dr) : 0.f;
        float b = (dc > 0) ? rsqrtf((float)dc) : 0.f;
        cf = attr[e] * a * b;
    }
    __syncthreads();
    if (t < R) lbase[t] = atomicAdd(&cursor[t], lcnt[t]);
    __syncthreads();
    if (e < n) {
        int pos = lbase[r] + rank;                       // relation-bucket position
        int sp = col_start[c] + atomicAdd(&ccur[c], 1);  // col-sorted position
        bk_row[pos] = rw;
        bk_dst[pos] = sp;
        bk_coef[pos] = cf;
        scoef[sp] = cf;
        styp[sp] = (unsigned char)r;
    }
}

// ---------- layer 1 gather: xb = bf16(z1) ----------
__global__ void k_phase1(const float* __restrict__ s1, const float* __restrict__ b1,
                         const int* __restrict__ col_start,
                         const unsigned char* __restrict__ styp,
                         const float* __restrict__ scoef,
                         unsigned* __restrict__ xb32) {
    __shared__ float ls1[R * D];
    __shared__ float lb[D];
    int t = threadIdx.x;
    ls1[t] = s1[t];
    ls1[t + 256] = s1[t + 256];
    if (t < D) lb[t] = b1[t];
    __syncthreads();
    int lane = t & 63;
    int c = blockIdx.x * 4 + (t >> 6);
    if (c >= EN) return;
    int st = col_start[c], en = col_start[c + 1];
    float a0 = 0.f, a1 = 0.f;
    for (int p = st; p < en; ++p) {
        float cf = scoef[p];
        int tp = styp[p];
        a0 += cf * ls1[tp * D + lane * 2];
        a1 += cf * ls1[tp * D + lane * 2 + 1];
    }
    a0 += lb[lane * 2]; a1 += lb[lane * 2 + 1];
    a0 = (a0 > 0.f) ? a0 : NEG * a0;
    a1 = (a1 > 0.f) ? a1 : NEG * a1;
    xb32[(size_t)c * 64 + lane] = pack2bf(a0, a1);
}

// ---------- MFMA GEMM (16x16x32, R5-proven): one wave per 16-edge tile ----------
__global__ __launch_bounds__(256)
void k_gemm(const unsigned short* __restrict__ xb, const unsigned short* __restrict__ wsw,
            const int* __restrict__ bk_row, const int* __restrict__ bk_dst,
            const float* __restrict__ bk_coef, const int* __restrict__ rbase,
            unsigned short* __restrict__ msgb) {
    const int r = blockIdx.y;
    const int base = rbase[r];
    const int cnt = rbase[r + 1] - base;
    const int t = threadIdx.x;
    const int tile = blockIdx.x * 4 + (t >> 6);
    __shared__ unsigned short xpose[4][16 * 144];   // 18 KB; wave-private regions
    if (tile * 16 >= cnt) return;           // wave-uniform early exit
    const int l = t & 63, q = l >> 4, n16 = l & 15;
    const int eidx = tile * 16 + n16;
    const bool valid = eidx < cnt;
    const int p = base + eidx;              // < EN + 64 (arrays padded)
    const int srow = bk_row[p];
    const int dp = bk_dst[p];
    const float cf = bk_coef[p];

    // B-frags: x[edge][k], 16 B per lane per K-step
    const unsigned short* xrow = xb + (size_t)srow * D;
    bf16x8 xf[4];
    #pragma unroll
    for (int s = 0; s < 4; ++s)
        xf[s] = *(const bf16x8*)(xrow + s * 32 + q * 8);

    // A-frags: swizzled W, L1/L2-resident
    const unsigned short* wr = wsw + ((size_t)r * 2048 + l) * 8;

    f32x4 acc[8];
    #pragma unroll
    for (int mt = 0; mt < 8; ++mt) acc[mt] = (f32x4){0.f, 0.f, 0.f, 0.f};

    #pragma unroll
    for (int s = 0; s < 4; ++s) {
        #pragma unroll
        for (int mt = 0; mt < 8; ++mt) {
            bf16x8 wf = *(const bf16x8*)(wr + (size_t)(s * 512 + mt * 64) * 8);
            acc[mt] = __builtin_amdgcn_mfma_f32_16x16x32_bf16(wf, xf[s], acc[mt], 0, 0, 0);
        }
    }

    // epilogue: scale, pack, transpose through wave-private LDS, coalesced store
    unsigned short* lbuf = xpose[t >> 6];
    const float c = valid ? cf : 0.f;
    #pragma unroll
    for (int mt = 0; mt < 8; ++mt) {
        uint2 u;
        u.x = pack2bf(acc[mt].x * c, acc[mt].y * c);
        u.y = pack2bf(acc[mt].z * c, acc[mt].w * c);
        *(uint2*)&lbuf[n16 * 144 + mt * 16 + q * 4] = u;
    }
    const int dpv = valid ? dp : EN;        // invalid edges -> dump row
    #pragma unroll
    for (int ro = 0; ro < 4; ++ro) {
        int e = ro * 4 + q;
        uint4 v = *(const uint4*)&lbuf[e * 144 + n16 * 8];
        int rdp = __shfl(dpv, e);
        *(uint4*)(msgb + (size_t)rdp * D + n16 * 8) = v;
    }
}

// ---------- phaseB: edge-major segmented reduction over 32 columns/block ----------
// Waves stream msgb rows sequentially (full 256 B coalesced reads), binary-search
// the owning column in a 33-entry LDS window, accumulate via LDS fp32 atomics.
// mode 2: z1 = xb; xb = z2 (bf16); zs = z1+z2 (bf16)
// mode 3: dout = (1 + zs + z3) * 0.25 (fp32)
__global__ __launch_bounds__(256)
void k_phaseB(const unsigned* __restrict__ msgb32, const float* __restrict__ bias,
              const int* __restrict__ col_start,
              unsigned* __restrict__ xb32, unsigned* __restrict__ zs32,
              float* __restrict__ dout, int mode) {
    __shared__ float acc[CPB * D];      // 16 KB
    __shared__ int   cs[CPB + 1];
    __shared__ float lb[D];
    const int t = threadIdx.x;
    const int c0 = blockIdx.x * CPB;
    if (t <= CPB) cs[t] = col_start[c0 + t];
    if (t < D) lb[t] = bias[t];
    #pragma unroll
    for (int i = 0; i < CPB * D / 256; ++i) acc[i * 256 + t] = 0.f;
    __syncthreads();
    const int e0 = cs[0];
    const int m = cs[CPB] - e0;
    const int lane = t & 63;
    const int w = t >> 6;
    for (int p = w; p < m; p += 4) {
        unsigned v = msgb32[(size_t)(e0 + p) * 64 + lane];
        int pg = e0 + p;
        int lo = 0, hi = CPB;          // invariant: cs[lo] <= pg < cs[hi]
        #pragma unroll
        for (int it = 0; it < 5; ++it) {
            int mid = (lo + hi) >> 1;
            if (cs[mid] <= pg) lo = mid; else hi = mid;
        }
        atomicAdd(&acc[lo * D + lane * 2], bflo(v));
        atomicAdd(&acc[lo * D + lane * 2 + 1], bfhi(v));
    }
    __syncthreads();
    // epilogue: thread t -> col cl = t>>3, features f0 = (t&7)*16 (linear stores)
    const int cl = t >> 3;
    const int f0 = (t & 7) * 16;
    const int c = c0 + cl;
    float vv[16];
    #pragma unroll
    for (int i = 0; i < 4; ++i)
        *(f32x4*)&vv[i * 4] = *(const f32x4*)&acc[cl * D + f0 + i * 4];
    #pragma unroll
    for (int i = 0; i < 16; ++i) {
        float a = vv[i] + lb[f0 + i];
        vv[i] = (a > 0.f) ? a : NEG * a;
    }
    size_t ix = (size_t)c * 64 + (t & 7) * 8;   // uint index into bf16x2 arrays
    if (mode == 2) {
        unsigned z1[8];
        *(uint4*)z1       = *(const uint4*)&xb32[ix];
        *(uint4*)(z1 + 4) = *(const uint4*)&xb32[ix + 4];
        unsigned z2[8], zs[8];
        #pragma unroll
        for (int i = 0; i < 8; ++i) {
            z2[i] = pack2bf(vv[2 * i], vv[2 * i + 1]);
            zs[i] = pack2bf(bflo(z1[i]) + vv[2 * i], bfhi(z1[i]) + vv[2 * i + 1]);
        }
        *(uint4*)&xb32[ix]     = *(uint4*)z2;
        *(uint4*)&xb32[ix + 4] = *(uint4*)(z2 + 4);
        *(uint4*)&zs32[ix]     = *(uint4*)zs;
        *(uint4*)&zs32[ix + 4] = *(uint4*)(zs + 4);
    } else {
        unsigned zs[8];
        *(uint4*)zs       = *(const uint4*)&zs32[ix];
        *(uint4*)(zs + 4) = *(const uint4*)&zs32[ix + 4];
        float o[16];
        #pragma unroll
        for (int i = 0; i < 8; ++i) {
            o[2 * i]     = (1.f + bflo(zs[i]) + vv[2 * i]) * 0.25f;
            o[2 * i + 1] = (1.f + bfhi(zs[i]) + vv[2 * i + 1]) * 0.25f;
        }
        float* dp = dout + (size_t)c * D + f0;
        #pragma unroll
        for (int i = 0; i < 4; ++i)
            *(float4*)(dp + i * 4) = *(float4*)&o[i * 4];
    }
}

extern "C" void kernel_launch(void* const* d_in, const int* in_sizes, int n_in,
                              void* d_out, int out_size, void* d_ws, size_t ws_size,
                              hipStream_t stream) {
    const int*   eidx = (const int*)d_in[0];     // [2, E]
    const int*   row  = eidx;
    const int*   col  = eidx + EN;
    const int*   etyp = (const int*)d_in[1];
    const float* attr = (const float*)d_in[2];
    const float* w1   = (const float*)d_in[3];
    const float* b1   = (const float*)d_in[4];
    const float* w2   = (const float*)d_in[5];
    const float* b2   = (const float*)d_in[6];
    const float* w3   = (const float*)d_in[7];
    const float* b3   = (const float*)d_in[8];
    float* dout = (float*)d_out;

    // workspace layout (~160 MB of the ~409.6 MB ws)
    char* wsb = (char*)d_ws;
    size_t off = 0;
    unsigned short* msgb = (unsigned short*)(wsb + off); off += (size_t)(EN + 1) * D * 2 + 512;
    unsigned short* xb   = (unsigned short*)(wsb + off); off += (size_t)EN * D * 2;
    unsigned short* zsb  = (unsigned short*)(wsb + off); off += (size_t)EN * D * 2;
    int*   col_start = (int*)(wsb + off); off += 800032;
    int*   cnt       = (int*)(wsb + off); off += (size_t)EN * 4;
    int*   rcnt      = (int*)(wsb + off); off += 16;      // contiguous after cnt!
    float* scoef     = (float*)(wsb + off); off += (size_t)EN * 4;
    unsigned char* styp = (unsigned char*)(wsb + off); off += 200064;
    int*   bk_row    = (int*)(wsb + off); off += (size_t)(EN + 64) * 4;
    int*   bk_dst    = (int*)(wsb + off); off += (size_t)(EN + 64) * 4;
    float* bk_coef   = (float*)(wsb + off); off += (size_t)(EN + 64) * 4;
    unsigned short* w2b = (unsigned short*)(wsb + off); off += 131072;
    unsigned short* w3b = (unsigned short*)(wsb + off); off += 131072;
    int*   part      = (int*)(wsb + off); off += 1024;
    int*   rbase     = (int*)(wsb + off); off += 32;
    int*   cursor    = (int*)(wsb + off); off += 16;
    float* s1        = (float*)(wsb + off); off += (size_t)R * D * 4;
    int*   ccur      = (int*)msgb;   // aliased: msgb not live until GEMM layer 2

    const int nE = EN;
    const int nBlkE = ceil_div(nE, 256);       // 782
    const int nScan = ceil_div(nE, 1024);      // 196
    dim3 blk(256);

    // histogram (one memset covers cnt + rcnt, contiguous)
    hipMemsetAsync(cnt, 0, (size_t)(nE + 4) * 4, stream);
    k_cnt<<<nBlkE, blk, 0, stream>>>(col, etyp, cnt, rcnt, nE);

    // scan cnt -> col_start (scan1 also swizzles W2/W3 + colsum(W1);
    // scan2 also does relation bases + bk_row pad; scan3 zeroes ccur)
    k_scan1<<<nScan + 66, blk, 0, stream>>>(cnt, part, nE, nScan,
                                            w1, w2, w3, w2b, w3b, s1);
    k_scan2<<<1, blk, 0, stream>>>(part, nScan, rcnt, rbase, cursor, col_start, bk_row);
    k_scan3<<<nScan, blk, 0, stream>>>(cnt, part, col_start, ccur, nE);

    // bucket + col-sort placement (+ coef)
    k_bucket<<<nBlkE, blk, 0, stream>>>(row, col, etyp, attr, cnt, col_start,
                                        cursor, ccur, bk_row, bk_dst, bk_coef,
                                        scoef, styp, nE);

    // layer 1 (x = ones)
    k_phase1<<<ceil_div(nE, 4), blk, 0, stream>>>(s1, b1, col_start, styp, scoef,
                                                  (unsigned*)xb);

    // layers 2,3
    dim3 gg(ceil_div(ceil_div(nE, 16), 4), R);
    k_gemm<<<gg, blk, 0, stream>>>(xb, w2b, bk_row, bk_dst, bk_coef, rbase, msgb);
    k_phaseB<<<EN / CPB, blk, 0, stream>>>((const unsigned*)msgb, b2, col_start,
                                           (unsigned*)xb, (unsigned*)zsb, dout, 2);
    k_gemm<<<gg, blk, 0, stream>>>(xb, w3b, bk_row, bk_dst, bk_coef, rbase, msgb);
    k_phaseB<<<EN / CPB, blk, 0, stream>>>((const unsigned*)msgb, b3, col_start,
                                           (unsigned*)xb, (unsigned*)zsb, dout, 3);
}